// Round 7
// baseline (54.791 us; speedup 1.0000x reference)
//
#include <hip/hip_runtime.h>
#include <math.h>

#define NN 384
#define DD 128
#define KCH 32
#define NCHUNK (NN / KCH)   // 12
#define NCLS 10
#define CMAX 64
#define STR 132             // B/A staging row stride (16B aligned)
#define CST (CMAX + 1)      // ccc row stride 65 -> conflict-free row AND column access
#define EPSF 1e-6f

// K1: B = X G^T, A = B G, prod[i]=|B_i|^2 (= x M x), p2[i]=|A_i|^2 (= x M^T M x),
//     out[i] = +inf (atomicMin target; re-initialized every call).
__global__ void __launch_bounds__(128) k_A(const float* __restrict__ X,
                                           const float* __restrict__ G,
                                           float* __restrict__ B,
                                           float* __restrict__ A,
                                           float* __restrict__ prod,
                                           float* __restrict__ p2,
                                           float* __restrict__ out) {
    __shared__ float Xi[DD];
    __shared__ float Bs[DD];
    __shared__ float rp[2], rq[2];
    const int i = blockIdx.x;
    const int t = threadIdx.x;

    if (t < DD / 4) ((float4*)Xi)[t] = ((const float4*)(X + (size_t)i * DD))[t];
    __syncthreads();

    float b = 0.f;
    const float* gr = G + (size_t)t * DD;
#pragma unroll
    for (int d = 0; d < DD; d += 4) {
        float4 g = *(const float4*)(gr + d);
        b = fmaf(g.x, Xi[d + 0], b);
        b = fmaf(g.y, Xi[d + 1], b);
        b = fmaf(g.z, Xi[d + 2], b);
        b = fmaf(g.w, Xi[d + 3], b);
    }
    Bs[t] = b;
    B[(size_t)i * DD + t] = b;
    __syncthreads();

    float a = 0.f;
#pragma unroll 8
    for (int c = 0; c < DD; ++c)
        a = fmaf(Bs[c], G[(size_t)c * DD + t], a);
    A[(size_t)i * DD + t] = a;

    float pp = b * b, qq = a * a;
#pragma unroll
    for (int off = 32; off > 0; off >>= 1) {
        pp += __shfl_down(pp, off);
        qq += __shfl_down(qq, off);
    }
    if ((t & 63) == 0) { rp[t >> 6] = pp; rq[t >> 6] = qq; }
    __syncthreads();
    if (t == 0) {
        prod[i] = rp[0] + rp[1];
        p2[i]   = rq[0] + rq[1];
        out[i]  = __builtin_inff();
    }
}

// K2: block (k-chunk of 32, class C). Local Grams (nc-bounded, symmetric ccc),
//     margins, 32-lane min over chunk k's, atomicMin into out[class rows].
__global__ void __launch_bounds__(256) k_margin(const float* __restrict__ B,
                                                const float* __restrict__ A,
                                                const float* __restrict__ prod,
                                                const float* __restrict__ p2,
                                                const int* __restrict__ y,
                                                float* __restrict__ out) {
    __shared__ float SC[CMAX][STR];      // class rows (B, then A)
    __shared__ float SK[KCH][STR];       // chunk rows (B, then A)
    __shared__ float ccc[CMAX][CST];     // csmd class x class (stride 65)
    __shared__ float cck[CMAX][KCH];     // csmd class x chunk
    __shared__ float ick[CMAX][KCH];     // invd class x chunk
    __shared__ float pc[CMAX], qc[CMAX];
    __shared__ float pk[KCH], qk[KCH];
    __shared__ int   yk[KCH];
    __shared__ int   list[CMAX];
    __shared__ int   cnt;

    const int t  = threadIdx.x;
    const int tx = t & 15, ty = t >> 4;  // 16x16 view (ccc tiles)
    const int kx = t & 31, ky = t >> 5;  // 32x8 view  (cck/ick/margins)
    const int C  = blockIdx.y;
    const int k0 = blockIdx.x * KCH;

    if (t == 0) cnt = 0;
    __syncthreads();
    for (int r = t; r < NN; r += 256) {
        if (y[r] == C) {
            int p = atomicAdd(&cnt, 1);
            if (p < CMAX) {
                list[p] = r;
                pc[p] = prod[r];
                qc[p] = p2[r];
            }
        }
    }
    if (t < KCH) {
        pk[t] = prod[k0 + t];
        qk[t] = p2[k0 + t];
        yk[t] = y[k0 + t];
    }
    __syncthreads();
    const int nc = min(cnt, CMAX);
    const int na = (nc + 15) >> 4;       // active 16-row tiles

    // ---- stage B rows
    for (int idx = t; idx < nc * 32; idx += 256) {
        int r = idx >> 5, q = idx & 31;
        *(float4*)&SC[r][q * 4] = ((const float4*)(B + (size_t)list[r] * DD))[q];
    }
    for (int idx = t; idx < KCH * 32; idx += 256) {
        int r = idx >> 5, q = idx & 31;
        *(float4*)&SK[r][q * 4] = ((const float4*)(B + (size_t)(k0 + r) * DD))[q];
    }
    __syncthreads();

    // ---- ccc: symmetric, upper tile pairs only, mirrored (stride-65 -> no conflicts)
    for (int a = 0; a < na; ++a) {
        for (int bb = a; bb < na; ++bb) {
            const int i = 16 * a + ty, j = 16 * bb + tx;
            float acc = 0.f;
#pragma unroll 4
            for (int d = 0; d < DD; d += 4) {
                const float4 bi = *(const float4*)&SC[i][d];
                const float4 bj = *(const float4*)&SC[j][d];
                acc = fmaf(bi.x, bj.x, acc);
                acc = fmaf(bi.y, bj.y, acc);
                acc = fmaf(bi.z, bj.z, acc);
                acc = fmaf(bi.w, bj.w, acc);
            }
            const float v = pc[i] + pc[j] - 2.f * acc;
            ccc[i][j] = v;
            if (a != bb) ccc[j][i] = v;
        }
    }
    // ---- cck: class x chunk csmd (rows i = ky + 8r, bounded by nc)
    {
        const int nr = (nc + 7) >> 3;
        for (int r = 0; r < nr; ++r) {
            const int i = ky + 8 * r;
            float acc = 0.f;
#pragma unroll 4
            for (int d = 0; d < DD; d += 4) {
                const float4 bk = *(const float4*)&SK[kx][d];
                const float4 bi = *(const float4*)&SC[i][d];
                acc = fmaf(bi.x, bk.x, acc);
                acc = fmaf(bi.y, bk.y, acc);
                acc = fmaf(bi.z, bk.z, acc);
                acc = fmaf(bi.w, bk.w, acc);
            }
            if (i < nc) cck[i][kx] = pc[i] + pk[kx] - 2.f * acc;
        }
    }
    __syncthreads();

    // ---- restage A rows; set diag(ccc)=+inf (j==i exclusion)
    for (int idx = t; idx < nc * 32; idx += 256) {
        int r = idx >> 5, q = idx & 31;
        *(float4*)&SC[r][q * 4] = ((const float4*)(A + (size_t)list[r] * DD))[q];
    }
    for (int idx = t; idx < KCH * 32; idx += 256) {
        int r = idx >> 5, q = idx & 31;
        *(float4*)&SK[r][q * 4] = ((const float4*)(A + (size_t)(k0 + r) * DD))[q];
    }
    if (t < nc) ccc[t][t] = __builtin_inff();
    __syncthreads();

    // ---- ick: invd class x chunk
    {
        const int nr = (nc + 7) >> 3;
        for (int r = 0; r < nr; ++r) {
            const int j = ky + 8 * r;
            float acc = 0.f;
#pragma unroll 4
            for (int d = 0; d < DD; d += 4) {
                const float4 ak = *(const float4*)&SK[kx][d];
                const float4 aj = *(const float4*)&SC[j][d];
                acc = fmaf(aj.x, ak.x, acc);
                acc = fmaf(aj.y, ak.y, acc);
                acc = fmaf(aj.z, ak.z, acc);
                acc = fmaf(aj.w, ak.w, acc);
            }
            if (j < nc) {
                const float c2 = qc[j] + qk[kx] - 2.f * acc;
                ick[j][kx] = 1.f / fmaxf(2.f * sqrtf(fmaxf(c2, EPSF)), EPSF);
            }
        }
    }
    __syncthreads();

    // ---- margins: m(i,k) = max_{j<nc} relu(cck[i][k]-ccc[i][j]) * ick[j][k];
    //      same-class k excluded; min over 32 k-lanes; atomicMin into out.
    {
        const bool kex = (yk[kx] == C);
        const int nr = (nc + 7) >> 3;
        for (int r = 0; r < nr; ++r) {
            const int i = ky + 8 * r;
            float m = 0.f;
            if (i < nc) {
                const float cik = cck[i][kx];
#pragma unroll 4
                for (int j = 0; j < nc; ++j) {
                    const float dlt = fmaxf(cik - ccc[i][j], 0.f);
                    m = fmaxf(m, dlt * ick[j][kx]);
                }
            }
            if (kex) m = __builtin_inff();
#pragma unroll
            for (int off = 1; off < 32; off <<= 1)
                m = fminf(m, __shfl_xor(m, off));
            if (kx == 0 && i < nc)
                atomicMin((int*)&out[list[i]], __float_as_int(m));
        }
    }
}

extern "C" void kernel_launch(void* const* d_in, const int* in_sizes, int n_in,
                              void* d_out, int out_size, void* d_ws, size_t ws_size,
                              hipStream_t stream) {
    const float* X = (const float*)d_in[0];
    const float* G = (const float*)d_in[1];
    const int*   y = (const int*)d_in[2];

    float* ws   = (float*)d_ws;
    float* B    = ws;                  // 384*128
    float* A    = B + NN * DD;         // 384*128
    float* prod = A + NN * DD;         // 384
    float* p2   = prod + NN;           // 384
    float* out  = (float*)d_out;

    k_A     <<<dim3(NN), dim3(DD), 0, stream>>>(X, G, B, A, prod, p2, out);
    k_margin<<<dim3(NCHUNK, NCLS), dim3(256), 0, stream>>>(B, A, prod, p2, y, out);
}

// Round 8
// 34.797 us; speedup vs baseline: 1.5746x; 1.5746x over previous
//
#include <hip/hip_runtime.h>
#include <math.h>

#define NN 384
#define DD 128
#define KCH 16
#define NCHUNK (NN / KCH)   // 24
#define NCLS 10
#define ISUB 4              // i-subtiles of 16 rows (CMAX = 64)
#define CMAX 64
#define STR 132             // LDS staging row stride (16B aligned)
#define EPSF 1e-6f

// K1: B = X G^T, A = B G, prod[i]=|B_i|^2 (= x M x), p2[i]=|A_i|^2 (= x M^T M x),
//     out[i] = +inf (atomicMin target; re-initialized every call).
__global__ void __launch_bounds__(128) k_A(const float* __restrict__ X,
                                           const float* __restrict__ G,
                                           float* __restrict__ B,
                                           float* __restrict__ A,
                                           float* __restrict__ prod,
                                           float* __restrict__ p2,
                                           float* __restrict__ out) {
    __shared__ float Xi[DD];
    __shared__ float Bs[DD];
    __shared__ float rp[2], rq[2];
    const int i = blockIdx.x;
    const int t = threadIdx.x;

    if (t < DD / 4) ((float4*)Xi)[t] = ((const float4*)(X + (size_t)i * DD))[t];
    __syncthreads();

    float b = 0.f;
    const float* gr = G + (size_t)t * DD;
#pragma unroll
    for (int d = 0; d < DD; d += 4) {
        float4 g = *(const float4*)(gr + d);
        b = fmaf(g.x, Xi[d + 0], b);
        b = fmaf(g.y, Xi[d + 1], b);
        b = fmaf(g.z, Xi[d + 2], b);
        b = fmaf(g.w, Xi[d + 3], b);
    }
    Bs[t] = b;
    B[(size_t)i * DD + t] = b;
    __syncthreads();

    float a = 0.f;
#pragma unroll 8
    for (int c = 0; c < DD; ++c)
        a = fmaf(Bs[c], G[(size_t)c * DD + t], a);
    A[(size_t)i * DD + t] = a;

    float pp = b * b, qq = a * a;
#pragma unroll
    for (int off = 32; off > 0; off >>= 1) {
        pp += __shfl_down(pp, off);
        qq += __shfl_down(qq, off);
    }
    if ((t & 63) == 0) { rp[t >> 6] = pp; rq[t >> 6] = qq; }
    __syncthreads();
    if (t == 0) {
        prod[i] = rp[0] + rp[1];
        p2[i]   = rq[0] + rq[1];
        out[i]  = __builtin_inff();
    }
}

// K2: block (k-chunk 16, class C, i-subtile 16). Deterministic ballot class list,
//     local Grams with 4-acc register tiling, margins, 16-lane k-min, atomicMin.
__global__ void __launch_bounds__(256) k_margin(const float* __restrict__ B,
                                                const float* __restrict__ A,
                                                const float* __restrict__ prod,
                                                const float* __restrict__ p2,
                                                const int* __restrict__ y,
                                                float* __restrict__ out) {
    __shared__ float SC[CMAX][STR];        // class rows (B, then A)
    __shared__ float SK[KCH][STR];         // chunk rows (B, then A)
    __shared__ float cij[16][CMAX + 1];    // csmd subset-i x class-j (stride 65)
    __shared__ float cik[16][KCH];         // csmd subset-i x chunk-k
    __shared__ float ick[CMAX][KCH];       // invd class-j x chunk-k
    __shared__ float pc[CMAX], qc[CMAX];
    __shared__ float pk[KCH], qk[KCH];
    __shared__ int   yk[KCH];
    __shared__ int   list[CMAX];
    __shared__ int   wcnt[6], woff[7];

    const int t    = threadIdx.x;
    const int C    = blockIdx.y;
    const int k0   = blockIdx.x * KCH;
    const int is   = blockIdx.z;
    const int wid  = t >> 6, lane = t & 63;
    const int u    = t & 15, v = t >> 4;   // (v,u): 16x16 thread view

    // ---- deterministic class list (ballot + popcount over 6 windows of 64)
    for (int w = wid; w < 6; w += 4) {
        unsigned long long m = __ballot(y[w * 64 + lane] == C);
        if (lane == 0) wcnt[w] = (int)__popcll(m);
    }
    __syncthreads();
    if (t == 0) {
        int s = 0;
        for (int w = 0; w < 6; ++w) { woff[w] = s; s += wcnt[w]; }
        woff[6] = s;
    }
    __syncthreads();
    const int nc = min(woff[6], CMAX);
    const int ibase = is * 16;
    if (ibase >= nc) return;               // block-uniform: whole block exits
    const int ni = min(16, nc - ibase);
    for (int w = wid; w < 6; w += 4) {
        const int r = w * 64 + lane;
        unsigned long long m = __ballot(y[r] == C);
        if (y[r] == C) {
            const int p = woff[w] + (int)__popcll(m & ((1ull << lane) - 1ull));
            if (p < CMAX) list[p] = r;
        }
    }
    __syncthreads();

    for (int p = t; p < nc; p += 256) { const int r = list[p]; pc[p] = prod[r]; qc[p] = p2[r]; }
    if (t < KCH) { pk[t] = prod[k0 + t]; qk[t] = p2[k0 + t]; yk[t] = y[k0 + t]; }
    // ---- stage B rows (class + chunk)
    for (int idx = t; idx < nc * 32; idx += 256) {
        const int r = idx >> 5, q = idx & 31;
        *(float4*)&SC[r][q * 4] = ((const float4*)(B + (size_t)list[r] * DD))[q];
    }
    for (int idx = t; idx < KCH * 32; idx += 256) {
        const int r = idx >> 5, q = idx & 31;
        *(float4*)&SK[r][q * 4] = ((const float4*)(B + (size_t)(k0 + r) * DD))[q];
    }
    __syncthreads();

    const int iv = ibase + (v < ni ? v : 0);   // clamped subset row (class-local)

    // ---- cij: csmd[i][j], 4 j-accumulators per thread (j = u, u+16, u+32, u+48)
    {
        float a0 = 0.f, a1 = 0.f, a2 = 0.f, a3 = 0.f;
#pragma unroll 2
        for (int d = 0; d < DD; d += 4) {
            const float4 bi = *(const float4*)&SC[iv][d];
            const float4 b0 = *(const float4*)&SC[u][d];
            const float4 b1 = *(const float4*)&SC[u + 16][d];
            const float4 b2 = *(const float4*)&SC[u + 32][d];
            const float4 b3 = *(const float4*)&SC[u + 48][d];
            a0 = fmaf(bi.x, b0.x, a0); a0 = fmaf(bi.y, b0.y, a0);
            a0 = fmaf(bi.z, b0.z, a0); a0 = fmaf(bi.w, b0.w, a0);
            a1 = fmaf(bi.x, b1.x, a1); a1 = fmaf(bi.y, b1.y, a1);
            a1 = fmaf(bi.z, b1.z, a1); a1 = fmaf(bi.w, b1.w, a1);
            a2 = fmaf(bi.x, b2.x, a2); a2 = fmaf(bi.y, b2.y, a2);
            a2 = fmaf(bi.z, b2.z, a2); a2 = fmaf(bi.w, b2.w, a2);
            a3 = fmaf(bi.x, b3.x, a3); a3 = fmaf(bi.y, b3.y, a3);
            a3 = fmaf(bi.z, b3.z, a3); a3 = fmaf(bi.w, b3.w, a3);
        }
        if (v < ni) {
            const float pi = pc[iv];
            cij[v][u] = pi + pc[u] - 2.f * a0;
            if (u + 16 < nc) cij[v][u + 16] = pi + pc[u + 16] - 2.f * a1;
            if (u + 32 < nc) cij[v][u + 32] = pi + pc[u + 32] - 2.f * a2;
            if (u + 48 < nc) cij[v][u + 48] = pi + pc[u + 48] - 2.f * a3;
        }
    }
    // ---- cik: csmd[i][k] (one dot per thread)
    {
        float acc = 0.f;
#pragma unroll 2
        for (int d = 0; d < DD; d += 4) {
            const float4 bi = *(const float4*)&SC[iv][d];
            const float4 bk = *(const float4*)&SK[u][d];
            acc = fmaf(bi.x, bk.x, acc); acc = fmaf(bi.y, bk.y, acc);
            acc = fmaf(bi.z, bk.z, acc); acc = fmaf(bi.w, bk.w, acc);
        }
        if (v < ni) cik[v][u] = pc[iv] + pk[u] - 2.f * acc;
    }
    __syncthreads();

    // ---- restage A rows; j==i exclusion on the diagonal slot
    for (int idx = t; idx < nc * 32; idx += 256) {
        const int r = idx >> 5, q = idx & 31;
        *(float4*)&SC[r][q * 4] = ((const float4*)(A + (size_t)list[r] * DD))[q];
    }
    for (int idx = t; idx < KCH * 32; idx += 256) {
        const int r = idx >> 5, q = idx & 31;
        *(float4*)&SK[r][q * 4] = ((const float4*)(A + (size_t)(k0 + r) * DD))[q];
    }
    if (t < ni) cij[t][ibase + t] = __builtin_inff();
    __syncthreads();

    // ---- ick: invd[j][k], 4 j-accumulators per thread
    {
        float a0 = 0.f, a1 = 0.f, a2 = 0.f, a3 = 0.f;
#pragma unroll 2
        for (int d = 0; d < DD; d += 4) {
            const float4 ak = *(const float4*)&SK[u][d];
            const float4 j0 = *(const float4*)&SC[v][d];
            const float4 j1 = *(const float4*)&SC[v + 16][d];
            const float4 j2 = *(const float4*)&SC[v + 32][d];
            const float4 j3 = *(const float4*)&SC[v + 48][d];
            a0 = fmaf(j0.x, ak.x, a0); a0 = fmaf(j0.y, ak.y, a0);
            a0 = fmaf(j0.z, ak.z, a0); a0 = fmaf(j0.w, ak.w, a0);
            a1 = fmaf(j1.x, ak.x, a1); a1 = fmaf(j1.y, ak.y, a1);
            a1 = fmaf(j1.z, ak.z, a1); a1 = fmaf(j1.w, ak.w, a1);
            a2 = fmaf(j2.x, ak.x, a2); a2 = fmaf(j2.y, ak.y, a2);
            a2 = fmaf(j2.z, ak.z, a2); a2 = fmaf(j2.w, ak.w, a2);
            a3 = fmaf(j3.x, ak.x, a3); a3 = fmaf(j3.y, ak.y, a3);
            a3 = fmaf(j3.z, ak.z, a3); a3 = fmaf(j3.w, ak.w, a3);
        }
        {
            const float c2 = qc[v] + qk[u] - 2.f * a0;
            ick[v][u] = 1.f / fmaxf(2.f * sqrtf(fmaxf(c2, EPSF)), EPSF);
        }
        if (v + 16 < nc) {
            const float c2 = qc[v + 16] + qk[u] - 2.f * a1;
            ick[v + 16][u] = 1.f / fmaxf(2.f * sqrtf(fmaxf(c2, EPSF)), EPSF);
        }
        if (v + 32 < nc) {
            const float c2 = qc[v + 32] + qk[u] - 2.f * a2;
            ick[v + 32][u] = 1.f / fmaxf(2.f * sqrtf(fmaxf(c2, EPSF)), EPSF);
        }
        if (v + 48 < nc) {
            const float c2 = qc[v + 48] + qk[u] - 2.f * a3;
            ick[v + 48][u] = 1.f / fmaxf(2.f * sqrtf(fmaxf(c2, EPSF)), EPSF);
        }
    }
    __syncthreads();

    // ---- margins: m(i,k) = max_j relu(cik - cij)*ick; same-class k -> +inf;
    //      min over 16 k-lanes; atomicMin into out[i].
    {
        float m = 0.f;
        if (v < ni) {
            const float ck = cik[v][u];
#pragma unroll 4
            for (int j = 0; j < nc; ++j)
                m = fmaxf(m, fmaxf(ck - cij[v][j], 0.f) * ick[j][u]);
        }
        if (yk[u] == C) m = __builtin_inff();
#pragma unroll
        for (int off = 1; off < 16; off <<= 1)
            m = fminf(m, __shfl_xor(m, off));
        if (u == 0 && v < ni)
            atomicMin((int*)&out[list[ibase + v]], __float_as_int(m));
    }
}

extern "C" void kernel_launch(void* const* d_in, const int* in_sizes, int n_in,
                              void* d_out, int out_size, void* d_ws, size_t ws_size,
                              hipStream_t stream) {
    const float* X = (const float*)d_in[0];
    const float* G = (const float*)d_in[1];
    const int*   y = (const int*)d_in[2];

    float* ws   = (float*)d_ws;
    float* B    = ws;                  // 384*128
    float* A    = B + NN * DD;         // 384*128
    float* prod = A + NN * DD;         // 384
    float* p2   = prod + NN;           // 384
    float* out  = (float*)d_out;

    k_A     <<<dim3(NN), dim3(DD), 0, stream>>>(X, G, B, A, prod, p2, out);
    k_margin<<<dim3(NCHUNK, NCLS, ISUB), dim3(256), 0, stream>>>(B, A, prod, p2, y, out);
}

// Round 9
// 24.790 us; speedup vs baseline: 2.2102x; 1.4037x over previous
//
#include <hip/hip_runtime.h>
#include <math.h>

#define NN 384
#define DD 128
#define NTILE (NN / 16)   // 24
#define EPSF 1e-6f
#define STR2 132          // staging row stride (16B aligned)
#define CMAX 64

// K1: B = X G^T, A = B G, prod[i]=|B_i|^2 (= x M x), p2[i]=|A_i|^2 (= x M^T M x),
//     out[i] = +inf (atomicMin target; re-initialized every call).
__global__ void __launch_bounds__(128) k_A(const float* __restrict__ X,
                                           const float* __restrict__ G,
                                           float* __restrict__ B,
                                           float* __restrict__ A,
                                           float* __restrict__ prod,
                                           float* __restrict__ p2,
                                           float* __restrict__ out) {
    __shared__ float Xi[DD];
    __shared__ float Bs[DD];
    __shared__ float rp[2], rq[2];
    const int i = blockIdx.x;
    const int t = threadIdx.x;

    if (t < DD / 4) ((float4*)Xi)[t] = ((const float4*)(X + (size_t)i * DD))[t];
    __syncthreads();

    float b = 0.f;
    const float* gr = G + (size_t)t * DD;
#pragma unroll
    for (int d = 0; d < DD; d += 4) {
        float4 g = *(const float4*)(gr + d);
        b = fmaf(g.x, Xi[d + 0], b);
        b = fmaf(g.y, Xi[d + 1], b);
        b = fmaf(g.z, Xi[d + 2], b);
        b = fmaf(g.w, Xi[d + 3], b);
    }
    Bs[t] = b;
    B[(size_t)i * DD + t] = b;
    __syncthreads();

    float a = 0.f;
#pragma unroll 8
    for (int c = 0; c < DD; ++c)
        a = fmaf(Bs[c], G[(size_t)c * DD + t], a);
    A[(size_t)i * DD + t] = a;

    float pp = b * b, qq = a * a;
#pragma unroll
    for (int off = 32; off > 0; off >>= 1) {
        pp += __shfl_down(pp, off);
        qq += __shfl_down(qq, off);
    }
    if ((t & 63) == 0) { rp[t >> 6] = pp; rq[t >> 6] = qq; }
    __syncthreads();
    if (t == 0) {
        prod[i] = rp[0] + rp[1];
        p2[i]   = rq[0] + rq[1];
        out[i]  = __builtin_inff();
    }
}

// K2: csmd[i][k] = prod[i]+prod[k]-2*dot(B_i,B_k)  (via A.X == B.B form kept as A.X:
//     here dot(A_i, X_k); identical fp order to the proven round-4 kernel)
//     invd[i][k] = 1/max(2*sqrt(max(p2[i]+p2[k]-2*dot(A_i,A_k), eps)), eps)
// Upper-triangle tiles only; one-shot staging (2 barriers); mirror via LDS transpose.
__global__ void __launch_bounds__(256) k_csmd(const float* __restrict__ X,
                                              const float* __restrict__ A,
                                              const float* __restrict__ prod,
                                              const float* __restrict__ p2,
                                              float* __restrict__ csmd,
                                              float* __restrict__ invd) {
    const int ti = blockIdx.y, tk = blockIdx.x;
    if (ti > tk) return;                 // lower triangle: whole block exits
    __shared__ float Ais[16][STR2], Xks[16][STR2], Aks[16][STR2];
    __shared__ float Tc[16][17], Tv[16][17];
    const int t = threadIdx.x;
    const int tx = t & 15, ty = t >> 4;
    const int i0 = ti * 16, k0 = tk * 16;

    // one-shot stage: 16 A_i rows, 16 X_k rows, 16 A_k rows (6 float4 per thread)
    for (int idx = t; idx < 1536; idx += 256) {
        const int sel = idx >> 9;                  // 0:Ai 1:Xk 2:Ak
        const int r   = (idx >> 5) & 15;
        const int q   = (idx & 31) << 2;
        const float* src = (sel == 0) ? (A + (size_t)(i0 + r) * DD + q)
                         : (sel == 1) ? (X + (size_t)(k0 + r) * DD + q)
                                      : (A + (size_t)(k0 + r) * DD + q);
        float* dst = (sel == 0) ? &Ais[r][q] : (sel == 1) ? &Xks[r][q] : &Aks[r][q];
        *(float4*)dst = *(const float4*)src;
    }
    __syncthreads();

    float dA = 0.f, dAA = 0.f;
#pragma unroll 8
    for (int d = 0; d < DD; d += 4) {
        const float4 aa = *(const float4*)&Ais[ty][d];
        const float4 xx = *(const float4*)&Xks[tx][d];
        const float4 ak = *(const float4*)&Aks[tx][d];
        dA  = fmaf(aa.x, xx.x, dA);  dA  = fmaf(aa.y, xx.y, dA);
        dA  = fmaf(aa.z, xx.z, dA);  dA  = fmaf(aa.w, xx.w, dA);
        dAA = fmaf(aa.x, ak.x, dAA); dAA = fmaf(aa.y, ak.y, dAA);
        dAA = fmaf(aa.z, ak.z, dAA); dAA = fmaf(aa.w, ak.w, dAA);
    }
    const int i = i0 + ty, k = k0 + tx;
    const float c1  = prod[i] + prod[k] - 2.f * dA;
    const float c2  = p2[i] + p2[k] - 2.f * dAA;
    const float inv = 1.f / fmaxf(2.f * sqrtf(fmaxf(c2, EPSF)), EPSF);
    csmd[(size_t)i * NN + k] = c1;
    invd[(size_t)i * NN + k] = inv;
    if (ti != tk) {                      // mirror tile, coalesced via LDS transpose
        Tc[tx][ty] = c1;
        Tv[tx][ty] = inv;
        __syncthreads();
        csmd[(size_t)(k0 + ty) * NN + i0 + tx] = Tc[ty][tx];
        invd[(size_t)(k0 + ty) * NN + i0 + tx] = Tv[ty][tx];
    }
}

// K3: out[i] = min_{k: y[k]!=y[i]} max_{j: y[j]==y[i], j!=i} relu(csmd[i,k]-csmd[i,j]) * invd[j,k]
// grid (384 rows x 2 k-halves), 192 threads; partial min merged via atomicMin (exact).
__global__ void __launch_bounds__(192) k_cube(const float* __restrict__ csmd,
                                              const float* __restrict__ invd,
                                              const int* __restrict__ y,
                                              float* __restrict__ out) {
    __shared__ float cvals[CMAX];
    __shared__ int   jidx[CMAX];
    __shared__ float red[192];
    __shared__ int   cnt;
    const int i = blockIdx.x;
    const int h = blockIdx.y;
    const int t = threadIdx.x;
    const int k = h * 192 + t;
    const int yi = y[i];
    if (t == 0) cnt = 0;
    __syncthreads();

    // build class-j list (both halves scanned by every block; order-free: max is exact)
    for (int r = t; r < NN; r += 192) {
        const float cr = csmd[(size_t)i * NN + r];
        if (y[r] == yi && r != i) {
            const int p = atomicAdd(&cnt, 1);
            if (p < CMAX) { cvals[p] = cr; jidx[p] = r; }
        }
    }
    __syncthreads();
    const int c = min(cnt, CMAX);

    const float cit = csmd[(size_t)i * NN + k];
    const int   yk  = y[k];
    float m = 0.f;
    const float* invcol = invd + k;
    int jj = 0;
    for (; jj + 4 <= c; jj += 4) {       // 4 independent L2 loads in flight
        const float v0 = invcol[(size_t)jidx[jj + 0] * NN];
        const float v1 = invcol[(size_t)jidx[jj + 1] * NN];
        const float v2 = invcol[(size_t)jidx[jj + 2] * NN];
        const float v3 = invcol[(size_t)jidx[jj + 3] * NN];
        m = fmaxf(m, fmaxf(cit - cvals[jj + 0], 0.f) * v0);
        m = fmaxf(m, fmaxf(cit - cvals[jj + 1], 0.f) * v1);
        m = fmaxf(m, fmaxf(cit - cvals[jj + 2], 0.f) * v2);
        m = fmaxf(m, fmaxf(cit - cvals[jj + 3], 0.f) * v3);
    }
    for (; jj < c; ++jj)
        m = fmaxf(m, fmaxf(cit - cvals[jj], 0.f) * invcol[(size_t)jidx[jj] * NN]);

    if (yk == yi) m = __builtin_inff();  // exclude same-class k
    red[t] = m;
    __syncthreads();
    if (t < 64) {
        float v = fminf(red[t], fminf(red[t + 64], red[t + 128]));
#pragma unroll
        for (int off = 32; off > 0; off >>= 1)
            v = fminf(v, __shfl_down(v, off));
        if (t == 0) atomicMin((int*)&out[i], __float_as_int(v));
    }
}

extern "C" void kernel_launch(void* const* d_in, const int* in_sizes, int n_in,
                              void* d_out, int out_size, void* d_ws, size_t ws_size,
                              hipStream_t stream) {
    const float* X = (const float*)d_in[0];
    const float* G = (const float*)d_in[1];
    const int*   y = (const int*)d_in[2];

    float* ws   = (float*)d_ws;
    float* B    = ws;                  // 384*128
    float* A    = B + NN * DD;         // 384*128
    float* prod = A + NN * DD;         // 384
    float* p2   = prod + NN;           // 384
    float* csmd = p2 + NN;             // 384*384
    float* invd = csmd + NN * NN;      // 384*384
    float* out  = (float*)d_out;

    k_A   <<<dim3(NN), dim3(DD), 0, stream>>>(X, G, B, A, prod, p2, out);
    k_csmd<<<dim3(NTILE, NTILE), dim3(256), 0, stream>>>(X, A, prod, p2, csmd, invd);
    k_cube<<<dim3(NN, 2), dim3(192), 0, stream>>>(csmd, invd, y, out);
}